// Round 5
// baseline (128.903 us; speedup 1.0000x reference)
//
#include <hip/hip_runtime.h>
#include <math.h>

// Problem constants (from reference)
#define NA 3
#define NC 80
#define CH 85              // NC+5
#define NB 16
#define HH 52
#define WW 52
#define HW 2704            // HH*WW
#define HWF4 676           // HW/4
#define NT 256             // num targets
#define NCELLS (NB*NA*HW)  // 129792
#define NBMW 4056          // bitmap words = ceil(NCELLS/32)
#define STRIDE_F 8.0f      // 416/52
#define IGN_THR 0.5f

// Tiling: 52 pixels/block (one grid row, 13 float4), 52 chunks x 48 ba.
// LDS swizzle addr(c,l) = c*54 + l + (c>>2): phase-2 per-lane address step
// = 4*54+1 = 217, odd mod 32 -> all banks visited -> conflict-free reads.
// (R4 had step ≡ 4 mod 32 -> 8-way conflicts ~2.9x on the transpose reads.)
#define TF4T 13            // float4s per channel row per tile
#define NF4T 1105          // CH * TF4T f4-elements per tile
#define LSTR 54
#define LDSW 4609          // 84*54 + 51 + 21 + 1 words = 18.4 KB -> 8 blk/CU
#define NBLK 2496          // 52 chunks * 48 (B*A)
#define NTAIL 269          // 256 winners + 12 zero-blocks + 1 partial-sum

#define SW(c, l) ((c) * LSTR + (l) + ((c) >> 2))

__device__ __forceinline__ float sigm(float z) { return 1.0f / (1.0f + expf(-z)); }
// -log(sigmoid(z)) = log1p(exp(-z));  -log(1-sigmoid(z)) = log1p(exp(z))
__device__ __forceinline__ float splus(float z) { return log1pf(expf(z)); }

// ws layout (bytes):
//   0    : float acc[16]  acc[0]=dense noobj, acc[1]=obj xywh+conf,
//                         acc[2]=cls, acc[3]=zeroed-cell noobj correction
//   64   : int cnts[4]    {wcount, zcount, done, pad}
//   128  : int   wofs[256]
//   1152 : float wtx[256]
//   2176 : float wty[256]
//   3200 : float wtw[256]
//   4224 : float wth[256]
//   5248 : int   wlabel[256]
//   6272 : int   zofs[768]
//   9344 : float partials[2496]
// total ~19.3 KB

// ---------------------------------------------------------------------------
// Kernel 1 (fused): blocks 0..2495 dense transform (float4 in/out via
// swizzled-LDS transpose) + per-block noobj partial; block 2496 target prep.
// ---------------------------------------------------------------------------
__global__ __launch_bounds__(256) void fused_kernel(
        const float* __restrict__ x, float* __restrict__ out,
        const float* __restrict__ target, float* __restrict__ acc,
        int* __restrict__ cnts, int* __restrict__ wofs,
        float* __restrict__ wtx, float* __restrict__ wty,
        float* __restrict__ wtw, float* __restrict__ wth,
        int* __restrict__ wlabel, int* __restrict__ zofs,
        float* __restrict__ partials) {
    __shared__ float lds[LDSW];        // prep block aliases it (needs 17.3 KB)
    __shared__ float red[4];
    int bid = blockIdx.x;
    int t = threadIdx.x;

    if (bid == NBLK) {
        // ---------------- prep block ----------------
        unsigned int* bm = (unsigned int*)lds;          // [NBMW]
        int* s_keyobj = (int*)lds + NBMW;               // [256]
        int* s_cnt = (int*)lds + NBMW + NT;             // {wcnt, zcnt}
        if (t < 16) acc[t] = 0.0f;
        if (t == 16) cnts[2] = 0;                       // done counter
        if (t == 0) { s_cnt[0] = 0; s_cnt[1] = 0; }
        for (int i = t; i < NBMW; i += 256) bm[i] = 0u;

        const float awc[3] = {10.f, 16.f, 33.f};
        const float ahc[3] = {13.f, 30.f, 23.f};
        float timg = target[t*6 + 0];
        float gxc  = target[t*6 + 1] * (float)WW;
        float gyc  = target[t*6 + 2] * (float)HH;
        float gw   = target[t*6 + 3] * (float)WW;
        float gh   = target[t*6 + 4] * (float)HH;
        int label  = (int)target[t*6 + 5];

        float best_iou = -1.0f;
        int best = 0, ignbits = 0;
        for (int a = 0; a < 3; a++) {
            float inter = fminf(awc[a], gw) * fminf(ahc[a], gh);
            float iou = inter / (awc[a]*ahc[a] + 1e-16f + gw*gh - inter);
            if (iou > best_iou) { best_iou = iou; best = a; }  // first-max
            if (iou > IGN_THR) ignbits |= (1 << a);
        }
        int img = (int)timg;
        int gi = (int)gxc, gj = (int)gyc;
        int pixel = gj * WW + gi;
        int cellbase = img * (NA * HW) + pixel;
        int keyobj = cellbase + best * HW;
        s_keyobj[t] = keyobj;
        __syncthreads();

        // winner iff no later target maps to same cell (fixed-trip scan:
        // independent LDS reads pipeline at throughput, not latency)
        bool dup = false;
        #pragma unroll 8
        for (int m = 0; m < NT; m++) {
            int k = s_keyobj[m];
            dup = dup || (m > t && k == keyobj);
        }
        if (!dup) {
            int p = atomicAdd(&s_cnt[0], 1);
            wofs[p] = (img * NA + best) * (CH * HW) + pixel;
            wtx[p] = gxc - floorf(gxc);
            wty[p] = gyc - floorf(gyc);
            wtw[p] = logf(gw / awc[best] + 1e-16f);
            wth[p] = logf(gh / ahc[best] + 1e-16f);
            wlabel[p] = label;
        }
        // distinct zeroed-noobj cells via bitmap (first setter appends)
        for (int a = 0; a < 3; a++) {
            bool flag = (a == best) || ((ignbits >> a) & 1);
            if (flag) {
                int key = cellbase + a * HW;
                unsigned int bit = 1u << (key & 31);
                unsigned int old = atomicOr(&bm[key >> 5], bit);
                if (!(old & bit)) {
                    int p = atomicAdd(&s_cnt[1], 1);
                    zofs[p] = ((img * NA + a) * CH + 4) * HW + pixel;
                }
            }
        }
        __syncthreads();
        if (t == 0) { cnts[0] = s_cnt[0]; cnts[1] = s_cnt[1]; }
        return;
    }

    // ---------------- dense transform block ----------------
    int chunk = bid % 52;            // grid row  (hc = chunk)
    int ba    = bid / 52;            // b*3 + a
    int a     = ba % NA;
    const float awc[3] = {10.f, 16.f, 33.f};
    const float ahc[3] = {13.f, 30.f, 23.f};

    // Phase 1: batched float4 loads (independent), transform -> swizzled LDS
    const float4* x4 = (const float4*)x + (size_t)ba * (CH * HWF4)
                                        + chunk * TF4T;
    float4 v[5];
    #pragma unroll
    for (int i = 0; i < 5; i++) {
        int idx = t + i * 256;
        if (idx < NF4T) {
            int c = idx / TF4T, q = idx - c * TF4T;
            v[i] = x4[c * HWF4 + q];
        }
    }
    float noobj = 0.0f;
    #pragma unroll
    for (int i = 0; i < 5; i++) {
        int idx = t + i * 256;
        if (idx < NF4T) {
            int c = idx / TF4T, q = idx - c * TF4T;
            float r[4] = {v[i].x, v[i].y, v[i].z, v[i].w};
            #pragma unroll
            for (int k = 0; k < 4; k++) {
                int l = q * 4 + k;               // wc (pixel in row) 0..51
                float z = r[k], o;
                if (c == 0)      o = (sigm(z) + (float)l) * STRIDE_F;
                else if (c == 1) o = (sigm(z) + (float)chunk) * STRIDE_F;
                else if (c == 2) o = expf(z) * awc[a];
                else if (c == 3) o = expf(z) * ahc[a];
                else {
                    o = sigm(z);
                    if (c == 4) noobj += splus(z);
                }
                lds[SW(c, l)] = o;
            }
        }
    }
    // reduce noobj partial across the block
    for (int off = 32; off > 0; off >>= 1)
        noobj += __shfl_down(noobj, off, 64);
    if ((t & 63) == 0) red[t >> 6] = noobj;
    __syncthreads();

    // Phase 2: float4 stores of [cell][channel]-ordered output
    float4* o4 = (float4*)out + (size_t)ba * (HW * CH / 4) + chunk * NF4T;
    #pragma unroll
    for (int i = 0; i < 5; i++) {
        int j = t + i * 256;
        if (j < NF4T) {
            int flat = 4 * j;
            int cell = flat / CH;            // local cell (pixel) 0..51
            int ch = flat - cell * CH;
            float4 w;
            float* pw = &w.x;
            #pragma unroll
            for (int k = 0; k < 4; k++) {
                int chk = ch + k, cek = cell;
                if (chk >= CH) { chk -= CH; cek += 1; }
                pw[k] = lds[SW(chk, cek)];
            }
            o4[j] = w;
        }
    }
    if (t == 0) partials[bid] = red[0] + red[1] + red[2] + red[3];
}

// ---------------------------------------------------------------------------
// Kernel 2 (tail): blocks 0..255 = winner gather; 256..267 = zero-cell noobj
// corrections; 268 = sum main-block partials. Last-finishing block (device-
// scope done counter + fences) combines accumulators and writes the scalar.
// ---------------------------------------------------------------------------
__global__ __launch_bounds__(64) void tail_kernel(
        const float* __restrict__ x, const int* __restrict__ cnts,
        const int* __restrict__ wofs, const float* __restrict__ wtx,
        const float* __restrict__ wty, const float* __restrict__ wtw,
        const float* __restrict__ wth, const int* __restrict__ wlabel,
        const int* __restrict__ zofs, const float* __restrict__ partials,
        float* __restrict__ acc, int* __restrict__ done,
        float* __restrict__ out_total) {
    int b = blockIdx.x;
    int lane = threadIdx.x;

    if (b < NT) {
        if (b < cnts[0]) {
            int ofs = wofs[b];
            int label = wlabel[b];
            const float* xp = x + ofs;
            float lcls;
            {   // class channels 0..63
                float z = xp[(size_t)(5 + lane) * HW];
                lcls = (lane == label) ? splus(-z) : splus(z);
            }
            if (lane < 16) {               // class channels 64..79
                int c = 64 + lane;
                float z = xp[(size_t)(5 + c) * HW];
                lcls += (c == label) ? splus(-z) : splus(z);
            }
            float other = 0.0f;
            if (lane == 0) {
                float z0 = xp[0];
                float z2 = xp[(size_t)2 * HW];
                float z4 = xp[(size_t)4 * HW];
                float cx = sigm(z0);
                float dx = cx - wtx[b], dy = cx - wty[b];  // ref bug: cx for y
                float dw = z2 - wtw[b], dh = z2 - wth[b];  // ref bug: pw for h
                other = dx*dx + dy*dy + dw*dw + dh*dh + splus(-z4);
            }
            for (int off = 32; off > 0; off >>= 1)
                lcls += __shfl_down(lcls, off, 64);
            if (lane == 0) {
                atomicAdd(&acc[1], other);
                atomicAdd(&acc[2], lcls);
            }
        }
    } else if (b < NT + 12) {
        int idx = (b - NT) * 64 + lane;
        float v = 0.0f;
        if (idx < cnts[1]) v = splus(x[zofs[idx]]);
        for (int off = 32; off > 0; off >>= 1)
            v += __shfl_down(v, off, 64);
        if (lane == 0) atomicAdd(&acc[3], v);
    } else {
        float s = 0.0f;
        for (int i = lane; i < NBLK; i += 64) s += partials[i];
        for (int off = 32; off > 0; off >>= 1)
            s += __shfl_down(s, off, 64);
        if (lane == 0) atomicAdd(&acc[0], s);
    }

    __threadfence();
    if (lane == 0) {
        int old = atomicAdd(done, 1);
        if (old == NTAIL - 1) {            // last block: finalize
            __threadfence();
            float a0 = atomicAdd(&acc[0], 0.0f);   // coherent reads
            float a1 = atomicAdd(&acc[1], 0.0f);
            float a2 = atomicAdd(&acc[2], 0.0f);
            float a3 = atomicAdd(&acc[3], 0.0f);
            float wc = (float)cnts[0];
            float n_obj = fmaxf(wc, 1.0f);
            float n_noobj = fmaxf((float)NCELLS - (float)cnts[1], 1.0f);
            float cls_den = fmaxf(80.0f * wc, 1.0f);
            out_total[0] = a1 / n_obj + a2 / cls_den
                         + 0.5f * ((a0 - a3) / n_noobj);
        }
    }
}

// ---------------------------------------------------------------------------
extern "C" void kernel_launch(void* const* d_in, const int* in_sizes, int n_in,
                              void* d_out, int out_size, void* d_ws, size_t ws_size,
                              hipStream_t stream) {
    (void)in_sizes; (void)n_in; (void)out_size; (void)ws_size;
    const float* x      = (const float*)d_in[0];
    const float* target = (const float*)d_in[1];
    float* out = (float*)d_out;

    char* ws = (char*)d_ws;
    float* acc      = (float*)(ws + 0);
    int*   cnts     = (int*)  (ws + 64);
    int*   wofs     = (int*)  (ws + 128);
    float* wtx      = (float*)(ws + 1152);
    float* wty      = (float*)(ws + 2176);
    float* wtw      = (float*)(ws + 3200);
    float* wth      = (float*)(ws + 4224);
    int*   wlabel   = (int*)  (ws + 5248);
    int*   zofs     = (int*)  (ws + 6272);
    float* partials = (float*)(ws + 9344);

    fused_kernel<<<NBLK + 1, 256, 0, stream>>>(
        x, out, target, acc, cnts, wofs, wtx, wty, wtw, wth, wlabel, zofs,
        partials);
    tail_kernel<<<NTAIL, 64, 0, stream>>>(
        x, cnts, wofs, wtx, wty, wtw, wth, wlabel, zofs, partials,
        acc, &cnts[2], out + (size_t)NB * NA * HW * CH);
}

// Round 6
// 120.708 us; speedup vs baseline: 1.0679x; 1.0679x over previous
//
#include <hip/hip_runtime.h>
#include <math.h>

// Problem constants (from reference)
#define NA 3
#define NC 80
#define CH 85              // NC+5
#define NB 16
#define HH 52
#define WW 52
#define HW 2704            // HH*WW
#define HWF4 676           // HW/4
#define NT 256             // num targets
#define NCELLS (NB*NA*HW)  // 129792
#define NBMW 4056          // bitmap words = ceil(NCELLS/32)
#define STRIDE_F 8.0f      // 416/52
#define IGN_THR 0.5f

// Tiling (R4 winner): 104 pixels/block (26 float4), 26 chunks x 48 ba.
// R5 lesson: 52-px tiles regressed (lane waste 14% + 2x per-block overhead,
// no occupancy gain) -> reverted. This round changes ONE thing vs R4:
// swizzled LDS addressing SW(c,l) = c*105 + l + (c>>2). Phase-2 transpose
// reads step 4*105+1 = 421 ≡ 5 (mod 32), odd -> all 32 banks -> the R4
// 8-way conflict (2.94x, m136) becomes free 2-way. Phase-1 writes unchanged.
#define TP 104
#define TF4 26
#define NF4 2210           // CH * TF4 f4-elements per tile
#define LSTR 105
#define LDSW 8945          // SW(84,103)+1 words = 35.8 KB -> 4 blk/CU (as R4)
#define NBLK 1248          // 26 chunks * 48 (B*A)
#define NTAIL 269          // 256 winners + 12 zero-blocks + 1 partial-sum

#define SW(c, l) ((c) * LSTR + (l) + ((c) >> 2))

__device__ __forceinline__ float sigm(float z) { return 1.0f / (1.0f + expf(-z)); }
// -log(sigmoid(z)) = log1p(exp(-z));  -log(1-sigmoid(z)) = log1p(exp(z))
__device__ __forceinline__ float splus(float z) { return log1pf(expf(z)); }

// ws layout (bytes):
//   0    : float acc[16]  acc[0]=dense noobj, acc[1]=obj xywh+conf,
//                         acc[2]=cls, acc[3]=zeroed-cell noobj correction
//   64   : int cnts[4]    {wcount, zcount, done, pad}
//   128  : int   wofs[256]
//   1152 : float wtx[256]
//   2176 : float wty[256]
//   3200 : float wtw[256]
//   4224 : float wth[256]
//   5248 : int   wlabel[256]
//   6272 : int   zofs[768]
//   9344 : float partials[1248]
// total 14336 B

// ---------------------------------------------------------------------------
// Kernel 1 (fused): blocks 0..1247 dense transform (float4 in/out via
// swizzled-LDS transpose) + per-block noobj partial; block 1248 target prep
// (winner dedupe via fixed-trip LDS scan, zero-cell dedupe via LDS bitmap).
// ---------------------------------------------------------------------------
__global__ __launch_bounds__(256) void fused_kernel(
        const float* __restrict__ x, float* __restrict__ out,
        const float* __restrict__ target, float* __restrict__ acc,
        int* __restrict__ cnts, int* __restrict__ wofs,
        float* __restrict__ wtx, float* __restrict__ wty,
        float* __restrict__ wtw, float* __restrict__ wth,
        int* __restrict__ wlabel, int* __restrict__ zofs,
        float* __restrict__ partials) {
    __shared__ float lds[LDSW];        // prep block aliases it (needs 17.3 KB)
    __shared__ float red[4];
    int bid = blockIdx.x;
    int t = threadIdx.x;

    if (bid == NBLK) {
        // ---------------- prep block ----------------
        unsigned int* bm = (unsigned int*)lds;          // [NBMW]
        int* s_keyobj = (int*)lds + NBMW;               // [256]
        int* s_cnt = (int*)lds + NBMW + NT;             // {wcnt, zcnt}
        if (t < 16) acc[t] = 0.0f;
        if (t == 16) cnts[2] = 0;                       // done counter
        if (t == 0) { s_cnt[0] = 0; s_cnt[1] = 0; }
        for (int i = t; i < NBMW; i += 256) bm[i] = 0u;

        const float awc[3] = {10.f, 16.f, 33.f};
        const float ahc[3] = {13.f, 30.f, 23.f};
        float timg = target[t*6 + 0];
        float gxc  = target[t*6 + 1] * (float)WW;
        float gyc  = target[t*6 + 2] * (float)HH;
        float gw   = target[t*6 + 3] * (float)WW;
        float gh   = target[t*6 + 4] * (float)HH;
        int label  = (int)target[t*6 + 5];

        float best_iou = -1.0f;
        int best = 0, ignbits = 0;
        for (int a = 0; a < 3; a++) {
            float inter = fminf(awc[a], gw) * fminf(ahc[a], gh);
            float iou = inter / (awc[a]*ahc[a] + 1e-16f + gw*gh - inter);
            if (iou > best_iou) { best_iou = iou; best = a; }  // first-max
            if (iou > IGN_THR) ignbits |= (1 << a);
        }
        int img = (int)timg;
        int gi = (int)gxc, gj = (int)gyc;
        int pixel = gj * WW + gi;
        int cellbase = img * (NA * HW) + pixel;
        int keyobj = cellbase + best * HW;
        s_keyobj[t] = keyobj;
        __syncthreads();

        // winner iff no later target maps to same cell (fixed-trip scan:
        // independent LDS reads pipeline at throughput, not latency)
        bool dup = false;
        #pragma unroll 8
        for (int m = 0; m < NT; m++) {
            int k = s_keyobj[m];
            dup = dup || (m > t && k == keyobj);
        }
        if (!dup) {
            int p = atomicAdd(&s_cnt[0], 1);
            wofs[p] = (img * NA + best) * (CH * HW) + pixel;
            wtx[p] = gxc - floorf(gxc);
            wty[p] = gyc - floorf(gyc);
            wtw[p] = logf(gw / awc[best] + 1e-16f);
            wth[p] = logf(gh / ahc[best] + 1e-16f);
            wlabel[p] = label;
        }
        // distinct zeroed-noobj cells via bitmap (first setter appends)
        for (int a = 0; a < 3; a++) {
            bool flag = (a == best) || ((ignbits >> a) & 1);
            if (flag) {
                int key = cellbase + a * HW;
                unsigned int bit = 1u << (key & 31);
                unsigned int old = atomicOr(&bm[key >> 5], bit);
                if (!(old & bit)) {
                    int p = atomicAdd(&s_cnt[1], 1);
                    zofs[p] = ((img * NA + a) * CH + 4) * HW + pixel;
                }
            }
        }
        __syncthreads();
        if (t == 0) { cnts[0] = s_cnt[0]; cnts[1] = s_cnt[1]; }
        return;
    }

    // ---------------- dense transform block ----------------
    int chunk = bid % 26;            // pixel chunk (104 px = 2 grid rows)
    int ba    = bid / 26;            // b*3 + a
    int a     = ba % NA;
    const float awc[3] = {10.f, 16.f, 33.f};
    const float ahc[3] = {13.f, 30.f, 23.f};

    // Phase 1: batched float4 loads (all independent), then transform -> LDS
    const float4* x4 = (const float4*)x + (size_t)ba * (CH * HWF4)
                                        + chunk * TF4;
    float4 v[9];
    #pragma unroll
    for (int i = 0; i < 9; i++) {
        int idx = t + i * 256;
        if (idx < NF4) {
            int c = idx / TF4, q = idx - c * TF4;
            v[i] = x4[c * HWF4 + q];
        }
    }
    float noobj = 0.0f;
    #pragma unroll
    for (int i = 0; i < 9; i++) {
        int idx = t + i * 256;
        if (idx < NF4) {
            int c = idx / TF4, q = idx - c * TF4;
            float r[4] = {v[i].x, v[i].y, v[i].z, v[i].w};
            #pragma unroll
            for (int k = 0; k < 4; k++) {
                int l = q * 4 + k;               // local pixel 0..103
                float z = r[k], o;
                if (c == 0) {
                    int wc = l - ((l >= WW) ? WW : 0);
                    o = (sigm(z) + (float)wc) * STRIDE_F;
                } else if (c == 1) {
                    int hc = chunk * 2 + ((l >= WW) ? 1 : 0);
                    o = (sigm(z) + (float)hc) * STRIDE_F;
                } else if (c == 2) {
                    o = expf(z) * awc[a];
                } else if (c == 3) {
                    o = expf(z) * ahc[a];
                } else {
                    o = sigm(z);
                    if (c == 4) noobj += splus(z);
                }
                lds[SW(c, l)] = o;
            }
        }
    }
    // reduce noobj partial across the block
    for (int off = 32; off > 0; off >>= 1)
        noobj += __shfl_down(noobj, off, 64);
    if ((t & 63) == 0) red[t >> 6] = noobj;
    __syncthreads();

    // Phase 2: float4 stores of [cell][channel]-ordered output
    float4* o4 = (float4*)out + (size_t)ba * (HW * CH / 4) + chunk * NF4;
    #pragma unroll
    for (int i = 0; i < 9; i++) {
        int j = t + i * 256;
        if (j < NF4) {
            int flat = 4 * j;
            int cell = flat / CH;            // local cell 0..103
            int ch = flat - cell * CH;
            float4 w;
            float* pw = &w.x;
            #pragma unroll
            for (int k = 0; k < 4; k++) {
                int chk = ch + k, cek = cell;
                if (chk >= CH) { chk -= CH; cek += 1; }
                pw[k] = lds[SW(chk, cek)];
            }
            o4[j] = w;
        }
    }
    if (t == 0) partials[bid] = red[0] + red[1] + red[2] + red[3];
}

// ---------------------------------------------------------------------------
// Kernel 2 (tail): blocks 0..255 = winner gather; 256..267 = zero-cell noobj
// corrections; 268 = sum main-block partials. Last-finishing block (device-
// scope done counter + fences) combines accumulators and writes the scalar.
// ---------------------------------------------------------------------------
__global__ __launch_bounds__(64) void tail_kernel(
        const float* __restrict__ x, const int* __restrict__ cnts,
        const int* __restrict__ wofs, const float* __restrict__ wtx,
        const float* __restrict__ wty, const float* __restrict__ wtw,
        const float* __restrict__ wth, const int* __restrict__ wlabel,
        const int* __restrict__ zofs, const float* __restrict__ partials,
        float* __restrict__ acc, int* __restrict__ done,
        float* __restrict__ out_total) {
    int b = blockIdx.x;
    int lane = threadIdx.x;

    if (b < NT) {
        if (b < cnts[0]) {
            int ofs = wofs[b];
            int label = wlabel[b];
            const float* xp = x + ofs;
            float lcls;
            {   // class channels 0..63
                float z = xp[(size_t)(5 + lane) * HW];
                lcls = (lane == label) ? splus(-z) : splus(z);
            }
            if (lane < 16) {               // class channels 64..79
                int c = 64 + lane;
                float z = xp[(size_t)(5 + c) * HW];
                lcls += (c == label) ? splus(-z) : splus(z);
            }
            float other = 0.0f;
            if (lane == 0) {
                float z0 = xp[0];
                float z2 = xp[(size_t)2 * HW];
                float z4 = xp[(size_t)4 * HW];
                float cx = sigm(z0);
                float dx = cx - wtx[b], dy = cx - wty[b];  // ref bug: cx for y
                float dw = z2 - wtw[b], dh = z2 - wth[b];  // ref bug: pw for h
                other = dx*dx + dy*dy + dw*dw + dh*dh + splus(-z4);
            }
            for (int off = 32; off > 0; off >>= 1)
                lcls += __shfl_down(lcls, off, 64);
            if (lane == 0) {
                atomicAdd(&acc[1], other);
                atomicAdd(&acc[2], lcls);
            }
        }
    } else if (b < NT + 12) {
        int idx = (b - NT) * 64 + lane;
        float v = 0.0f;
        if (idx < cnts[1]) v = splus(x[zofs[idx]]);
        for (int off = 32; off > 0; off >>= 1)
            v += __shfl_down(v, off, 64);
        if (lane == 0) atomicAdd(&acc[3], v);
    } else {
        float s = 0.0f;
        for (int i = lane; i < NBLK; i += 64) s += partials[i];
        for (int off = 32; off > 0; off >>= 1)
            s += __shfl_down(s, off, 64);
        if (lane == 0) atomicAdd(&acc[0], s);
    }

    __threadfence();
    if (lane == 0) {
        int old = atomicAdd(done, 1);
        if (old == NTAIL - 1) {            // last block: finalize
            __threadfence();
            float a0 = atomicAdd(&acc[0], 0.0f);   // coherent reads
            float a1 = atomicAdd(&acc[1], 0.0f);
            float a2 = atomicAdd(&acc[2], 0.0f);
            float a3 = atomicAdd(&acc[3], 0.0f);
            float wc = (float)cnts[0];
            float n_obj = fmaxf(wc, 1.0f);
            float n_noobj = fmaxf((float)NCELLS - (float)cnts[1], 1.0f);
            float cls_den = fmaxf(80.0f * wc, 1.0f);
            out_total[0] = a1 / n_obj + a2 / cls_den
                         + 0.5f * ((a0 - a3) / n_noobj);
        }
    }
}

// ---------------------------------------------------------------------------
extern "C" void kernel_launch(void* const* d_in, const int* in_sizes, int n_in,
                              void* d_out, int out_size, void* d_ws, size_t ws_size,
                              hipStream_t stream) {
    (void)in_sizes; (void)n_in; (void)out_size; (void)ws_size;
    const float* x      = (const float*)d_in[0];
    const float* target = (const float*)d_in[1];
    float* out = (float*)d_out;

    char* ws = (char*)d_ws;
    float* acc      = (float*)(ws + 0);
    int*   cnts     = (int*)  (ws + 64);
    int*   wofs     = (int*)  (ws + 128);
    float* wtx      = (float*)(ws + 1152);
    float* wty      = (float*)(ws + 2176);
    float* wtw      = (float*)(ws + 3200);
    float* wth      = (float*)(ws + 4224);
    int*   wlabel   = (int*)  (ws + 5248);
    int*   zofs     = (int*)  (ws + 6272);
    float* partials = (float*)(ws + 9344);

    fused_kernel<<<NBLK + 1, 256, 0, stream>>>(
        x, out, target, acc, cnts, wofs, wtx, wty, wtw, wth, wlabel, zofs,
        partials);
    tail_kernel<<<NTAIL, 64, 0, stream>>>(
        x, cnts, wofs, wtx, wty, wtw, wth, wlabel, zofs, partials,
        acc, &cnts[2], out + (size_t)NB * NA * HW * CH);
}